// Round 1
// baseline (11842.681 us; speedup 1.0000x reference)
//
#include <hip/hip_runtime.h>
#include <hip/hip_bf16.h>
#include <stdint.h>

#define B_   64
#define T_   1024
#define D_   300
#define H_   512
#define G4H  2048
#define KP   320   // K padded to multiple of 32 for the x-proj GEMM

typedef __attribute__((ext_vector_type(8))) short short8;   // 8 x bf16 (4 VGPRs)
typedef __attribute__((ext_vector_type(4))) float f32x4;
typedef unsigned long long ull;

__device__ __forceinline__ unsigned short f2bf(float v) {
    __hip_bfloat16 h = __float2bfloat16(v);
    return *reinterpret_cast<unsigned short*>(&h);
}
__device__ __forceinline__ float bf2f(unsigned u) {      // low 16 bits = bf16
    return __uint_as_float(u << 16);
}
__device__ __forceinline__ float sigm(float x) { return 1.f / (1.f + __expf(-x)); }
__device__ __forceinline__ float tanhfast(float x) {
    float e = __expf(2.f * x);            // inf-safe: x>>0 -> 1, x<<0 -> -1
    return 1.f - 2.f / (e + 1.f);
}

#define ASYNC16(g, l)                                                        \
    __builtin_amdgcn_global_load_lds(                                        \
        (const __attribute__((address_space(1))) void*)(g),                  \
        (__attribute__((address_space(3))) void*)(l), 16, 0, 0)

// ---------------------------------------------------------------------------
// Kernel 1: essays fp32 [65536][300] -> bf16 [65536][320] (zero-padded K)
// ---------------------------------------------------------------------------
__global__ void cvt_essays(const float* __restrict__ es, unsigned short* __restrict__ Ab) {
    unsigned i = blockIdx.x * 256u + threadIdx.x;       // exactly 65536*320 threads
    unsigned row = i / KP;
    unsigned col = i - row * KP;
    float v = (col < D_) ? es[(size_t)row * D_ + col] : 0.f;
    Ab[i] = f2bf(v);
}

// ---------------------------------------------------------------------------
// Kernel 2: Wx transpose+pad -> bf16 WxT[2048][320]
// ---------------------------------------------------------------------------
__global__ void cvt_misc(const float* __restrict__ Wl, unsigned short* __restrict__ Bt) {
    unsigned i = blockIdx.x * 256u + threadIdx.x;       // exactly 2048*320 threads
    unsigned n = i / KP, k = i - n * KP;
    float v = (k < D_) ? Wl[(size_t)k * G4H + n] : 0.f;   // Wx rows 0..299
    Bt[i] = f2bf(v);
}

// ---------------------------------------------------------------------------
// Kernel 2b: Wh transpose -> bf16 WhTg[2048][512] (coalesced block staging)
// ---------------------------------------------------------------------------
__global__ void cvt_wh(const float* __restrict__ Wl, unsigned short* __restrict__ WhTg) {
    unsigned i = blockIdx.x * 256u + threadIdx.x;       // 2048*512 threads
    unsigned gc = i & 2047u, k = i >> 11;
    WhTg[(size_t)gc * 512 + k] = f2bf(Wl[(size_t)(300 + k) * G4H + gc]);
}

// ---------------------------------------------------------------------------
// Kernel 3: x_proj GEMM -> xpr in the NEW recurrence layout:
//   per (t, g=batch-group, sl=j-slice of 32): 256 thread-slots x 8 bf16
//   idx = (((t*4+g)*16+sl)*256 + tid)*8 + u*4 + gate
// where the lstm thread tid = w*64 + q*16 + ln owns
//   b  = q*4 + (ln&3),  jl(u) = w*8 + u*4 + (ln>>2),  u in {0,1}
// so each lstm thread reads ONE 16B chunk per step per group.
// ---------------------------------------------------------------------------
__global__ __launch_bounds__(256) void gemm_xp(
    const unsigned short* __restrict__ Ab,   // [65536][320] bf16
    const unsigned short* __restrict__ Bt,   // [2048][320]  bf16 (WxT)
    const float* __restrict__ bias,          // [2048]
    unsigned short* __restrict__ xpr)        // [65536*2048] bf16, permuted
{
    __shared__ __align__(16) unsigned short Al[128 * 32];
    __shared__ __align__(16) unsigned short Bl[128 * 32];
    const int tid = threadIdx.x;
    const int w = tid >> 6, lane = tid & 63;
    const int ln = lane & 15, q = lane >> 4;
    const int bx = blockIdx.x;
    const int m0 = (bx >> 4) * 128;          // consecutive blocks share the A tile
    const int n0 = (bx & 15) * 128;
    const int wr = w >> 1, wc = w & 1;

    f32x4 acc[4][4];
#pragma unroll
    for (int i = 0; i < 4; i++)
#pragma unroll
        for (int j = 0; j < 4; j++) acc[i][j] = (f32x4){0.f, 0.f, 0.f, 0.f};

    for (int k0 = 0; k0 < KP; k0 += 32) {
#pragma unroll
        for (int it = 0; it < 2; ++it) {
            int s = it * 4 + w;              // wave-uniform segment id
            int c = s * 64 + lane;           // 16B chunk id, 0..511
            int r = c >> 2;                  // tile row 0..127
            int ko = (c & 3) * 8;            // k offset in elements
            ASYNC16(Ab + (size_t)(m0 + r) * KP + k0 + ko, &Al[s * 512]);
            ASYNC16(Bt + (size_t)(n0 + r) * KP + k0 + ko, &Bl[s * 512]);
        }
        __syncthreads();
        short8 af[4], bf[4];
#pragma unroll
        for (int mt = 0; mt < 4; ++mt)
            af[mt] = *(const short8*)&Al[(wr * 64 + mt * 16 + ln) * 32 + q * 8];
#pragma unroll
        for (int nt = 0; nt < 4; ++nt)
            bf[nt] = *(const short8*)&Bl[(wc * 64 + nt * 16 + ln) * 32 + q * 8];
#pragma unroll
        for (int mt = 0; mt < 4; ++mt)
#pragma unroll
            for (int nt = 0; nt < 4; ++nt)
                acc[mt][nt] = __builtin_amdgcn_mfma_f32_16x16x32_bf16(af[mt], bf[nt], acc[mt][nt], 0, 0, 0);
        __syncthreads();
    }
#pragma unroll
    for (int mt = 0; mt < 4; ++mt) {
#pragma unroll
        for (int nt = 0; nt < 4; ++nt) {
            int col = n0 + wc * 64 + nt * 16 + ln;
            int gate = col >> 9, j9 = col & 511;
            int sl = j9 >> 5, jl = j9 & 31;
            int wq  = jl >> 3;               // lstm wave
            int uu  = (jl >> 2) & 1;         // lstm col-tile
            int kk2 = jl & 3;                // lstm (ln>>2)
            float bb = bias[col];
#pragma unroll
            for (int r = 0; r < 4; ++r) {
                int row = m0 + wr * 64 + mt * 16 + q * 4 + r;   // C/D: col=lane&15, row=quad*4+reg
                int t = row & 1023, bglob = row >> 10;
                int g = bglob >> 4, b = bglob & 15;
                int tidl = wq * 64 + (b >> 2) * 16 + kk2 * 4 + (b & 3);
                size_t idx = ((((size_t)t * 4 + g) * 16 + sl) * 256 + tidl) * 8
                             + uu * 4 + gate;
                xpr[idx] = f2bf(acc[mt][nt][r] + bb);
            }
        }
    }
}

// ---------------------------------------------------------------------------
// Kernel 4: persistent LSTM recurrence, 4-group time-multiplexed.
// 16 blocks (one per 32-wide j-slice) x 256 threads; each block serves ALL
// four batch groups, rotating phases g=0..3 each step. While group g's h is
// in flight through the fabric (device-scope store -> L3 -> poll load), the
// block computes the other three groups: period = max(4*C, RTT) instead of
// C + RTT serial.
//   - Wh slice held in REGISTERS (bv[2][16] short8 = 128 VGPR/lane; shared by
//     all groups). No LDS B-operand traffic, no WhT staging.
//   - Gate columns interleaved (col c: gate=c&3, jl=c>>2) so a 4-lane shfl
//     4x4 transpose replaces the gbuf LDS round-trip; 1 barrier per phase.
//   - Poll loads for (group q, step ts) issued exactly 2 phases after the
//     producing store (even phases -> vE, odd -> vO), so they land fresh.
//   - h transport identical to the proven scheme: fp32, 2-bit step tag in
//     mantissa LSBs, buffers [2][64][512], per-dword retry, skew<=1 per group
//     (a block cannot pass phase g of step t without full h_g(t)), 0xAA
//     poison = tag 2 never collides with first-read tags 0,1.
// ---------------------------------------------------------------------------
__global__ __launch_bounds__(256, 1) void lstm_rec(
    const unsigned short* __restrict__ WhTg, // [2048][512] bf16 (pre-transposed Wh)
    const unsigned short* __restrict__ xpr,  // permuted x_proj (see gemm_xp)
    unsigned* __restrict__ hfp,              // [2][64][512] fp32 h, tag in low bits
    float* __restrict__ hmean)               // [64][512] fp32
{
    __shared__ __align__(16) unsigned short hl[4][16 * 520];  // per-group h, pad 520

    const int tid = threadIdx.x;
    const int sl  = blockIdx.x;              // j-slice 0..15 (32 j's)
    const int w = tid >> 6, lane = tid & 63, ln = lane & 15, q = lane >> 4;
    const int m = ln & 3;

    // ---- one-time: this wave's 32 Wh columns (gate-interleaved) -> registers
    short8 bv[2][16];
#pragma unroll
    for (int u = 0; u < 2; ++u) {
        int gc = (ln & 3) * 512 + 32 * sl + w * 8 + u * 4 + (ln >> 2);
        const unsigned short* wp = WhTg + (size_t)gc * 512 + q * 8;
#pragma unroll
        for (int kk = 0; kk < 16; ++kk)
            bv[u][kk] = *(const short8*)(wp + kk * 32);
    }
    // ---- h(0) = 0: zero all 4 hl buffers (4*16*520 shorts = 16640 dwords)
    for (int i2 = tid; i2 < 16640; i2 += 256) ((unsigned*)hl)[i2] = 0u;
    __syncthreads();

    float cst[4][2]  = {{0.f,0.f},{0.f,0.f},{0.f,0.f},{0.f,0.f}};
    float hsum[4][2] = {{0.f,0.f},{0.f,0.f},{0.f,0.f},{0.f,0.f}};
    short8 xc[4], xn[4];
#pragma unroll
    for (int g = 0; g < 4; ++g)
        xc[g] = *(const short8*)&xpr[(((size_t)g * 16 + sl) * 256 + tid) * 8];

    ull vE[16], vO[16];                      // in-flight polls, even/odd phases

    for (int t = 0; t < T_; ++t) {
#pragma unroll
        for (int p = 0; p < 4; ++p) {
            const int g = p;
            ull* v = (p & 1) ? vO : vE;
            // ---- finish poll of h_g(t) (loads issued 2 phases ago)
            if (t > 0) {
                const ull* src = (const ull*)(hfp + (size_t)(t & 1) * 32768 + g * 8192);
                const unsigned want = (unsigned)((t >> 1) & 3);
                while (true) {
                    unsigned bad = 0u;
#pragma unroll
                    for (int i = 0; i < 16; ++i) {
                        unsigned lo = (unsigned)v[i], hi = (unsigned)(v[i] >> 32);
                        bad |= ((((lo & 3u) ^ want) | ((hi & 3u) ^ want)) != 0u) ? (1u << i) : 0u;
                    }
                    if (!bad) break;
#pragma unroll
                    for (int i = 0; i < 16; ++i)
                        if (bad & (1u << i))
                            v[i] = __hip_atomic_load(src + tid + (i << 8),
                                                     __ATOMIC_RELAXED, __HIP_MEMORY_SCOPE_AGENT);
                }
                // decode fp32(tagged) -> bf16 pair -> hl[g]; thread owns col-pair tid of every row
#pragma unroll
                for (int i = 0; i < 16; ++i) {
                    unsigned uu = (unsigned)f2bf(__uint_as_float((unsigned)v[i]))
                                | ((unsigned)f2bf(__uint_as_float((unsigned)(v[i] >> 32))) << 16);
                    *(unsigned*)((char*)&hl[g][0] + i * 1040 + tid * 4) = uu;
                }
            }
            // ---- xp(t+1) prefetch for this group (one 16B load)
            if (t + 1 < T_)
                xn[g] = *(const short8*)&xpr[((((size_t)(t + 1) * 4 + g) * 16 + sl) * 256 + tid) * 8];
            __syncthreads();

            // ---- gates = h_g(t) @ Wh-slice : 2 col-tiles x 2 K-half chains
            f32x4 a0 = (f32x4){0.f,0.f,0.f,0.f}, a1 = (f32x4){0.f,0.f,0.f,0.f};
            f32x4 b0 = (f32x4){0.f,0.f,0.f,0.f}, b1 = (f32x4){0.f,0.f,0.f,0.f};
#pragma unroll
            for (int kk = 0; kk < 8; ++kk) {
                short8 av = *(const short8*)&hl[g][ln * 520 + kk * 32 + q * 8];
                a0 = __builtin_amdgcn_mfma_f32_16x16x32_bf16(av, bv[0][kk], a0, 0, 0, 0);
                a1 = __builtin_amdgcn_mfma_f32_16x16x32_bf16(av, bv[1][kk], a1, 0, 0, 0);
            }
#pragma unroll
            for (int kk = 8; kk < 16; ++kk) {
                short8 av = *(const short8*)&hl[g][ln * 520 + kk * 32 + q * 8];
                b0 = __builtin_amdgcn_mfma_f32_16x16x32_bf16(av, bv[0][kk], b0, 0, 0, 0);
                b1 = __builtin_amdgcn_mfma_f32_16x16x32_bf16(av, bv[1][kk], b1, 0, 0, 0);
            }
            // ---- per col-tile: transpose 4x4 in 4-lane groups, elementwise, store
#pragma unroll
            for (int u = 0; u < 2; ++u) {
                f32x4 ca = u ? a1 : a0, cb = u ? b1 : b0;
                float x0 = ca[0] + cb[0], x1 = ca[1] + cb[1];
                float x2 = ca[2] + cb[2], x3 = ca[3] + cb[3];
                // lanes 4k+m hold the 4 gates (lane dim) of jl=w*8+u*4+k, rows q*4+r
                float s0 = (m & 1) ? x0 : x1, s1 = (m & 1) ? x2 : x3;
                s0 = __shfl_xor(s0, 1); s1 = __shfl_xor(s1, 1);
                if (m & 1) { x0 = s0; x2 = s1; } else { x1 = s0; x3 = s1; }
                float u0 = (m & 2) ? x0 : x2, u1 = (m & 2) ? x1 : x3;
                u0 = __shfl_xor(u0, 2); u1 = __shfl_xor(u1, 2);
                if (m & 2) { x0 = u0; x1 = u1; } else { x2 = u0; x3 = u1; }
                // now x0..x3 = i,j,f,o (Wh part) for (b=q*4+m, jl=w*8+u*4+(ln>>2))
                float ai  = x0 + bf2f((unsigned)(unsigned short)xc[g][u * 4 + 0]);
                float aj  = x1 + bf2f((unsigned)(unsigned short)xc[g][u * 4 + 1]);
                float af_ = x2 + bf2f((unsigned)(unsigned short)xc[g][u * 4 + 2]);
                float ao  = x3 + bf2f((unsigned)(unsigned short)xc[g][u * 4 + 3]);
                float si = sigm(ai), tj = tanhfast(aj);
                float sf = sigm(af_ + 1.0f), so = sigm(ao);
                cst[g][u] = cst[g][u] * sf + si * tj;
                float h = tanhfast(cst[g][u]) * so;
                hsum[g][u] += h;
                unsigned hb = (__float_as_uint(h) & ~3u) | (unsigned)(((t + 1) >> 1) & 3);
                int b = q * 4 + m, jl = w * 8 + u * 4 + (ln >> 2);
                __hip_atomic_store(hfp + (size_t)((t + 1) & 1) * 32768 + (g * 16 + b) * 512 + 32 * sl + jl,
                                   hb, __ATOMIC_RELAXED, __HIP_MEMORY_SCOPE_AGENT);
            }
            xc[g] = xn[g];
            // ---- issue poll for group (p+2)&3, consumed exactly 2 phases later
            {
                const int gq = (p + 2) & 3;
                const int ts = (p < 2) ? t : (t + 1);
                if (ts >= 1 && ts < T_) {
                    const ull* src2 = (const ull*)(hfp + (size_t)(ts & 1) * 32768 + gq * 8192);
#pragma unroll
                    for (int i = 0; i < 16; ++i)
                        v[i] = __hip_atomic_load(src2 + tid + (i << 8),
                                                 __ATOMIC_RELAXED, __HIP_MEMORY_SCOPE_AGENT);
                }
            }
        }
    }
#pragma unroll
    for (int g = 0; g < 4; ++g)
#pragma unroll
        for (int u = 0; u < 2; ++u) {
            int b = q * 4 + m, jl = w * 8 + u * 4 + (ln >> 2);
            hmean[(size_t)(g * 16 + b) * 512 + 32 * sl + jl] = hsum[g][u] * (1.f / 1024.f);
        }
}

// ---------------------------------------------------------------------------
// Kernel 5: preds = sigmoid(hmean @ W_dense + b_dense), one wave per batch row
// ---------------------------------------------------------------------------
__global__ void dense_out(const float* __restrict__ hmean, const float* __restrict__ Wd,
                          const float* __restrict__ bd, float* __restrict__ out) {
    int bb = blockIdx.x;
    int lane = threadIdx.x;
    float p = 0.f;
    for (int e = lane; e < H_; e += 64) p += hmean[(size_t)bb * H_ + e] * Wd[e];
#pragma unroll
    for (int off = 32; off; off >>= 1) p += __shfl_down(p, off);
    if (lane == 0) out[bb] = 1.f / (1.f + __expf(-(p + bd[0])));
}

// ---------------------------------------------------------------------------
extern "C" void kernel_launch(void* const* d_in, const int* in_sizes, int n_in,
                              void* d_out, int out_size, void* d_ws, size_t ws_size,
                              hipStream_t stream) {
    const float* essays  = (const float*)d_in[0];
    const float* W_lstm  = (const float*)d_in[1];
    const float* b_lstm  = (const float*)d_in[2];
    const float* W_dense = (const float*)d_in[3];
    const float* b_dense = (const float*)d_in[4];
    float* out = (float*)d_out;

    char* ws = (char*)d_ws;
    unsigned short* xp   = (unsigned short*)(ws);                   // 256 MB (permuted)
    unsigned short* Ab   = (unsigned short*)(ws + 268435456ull);    // 40 MB (dead after gemm_xp)
    unsigned short* Bt   = (unsigned short*)(ws + 310378496ull);    // 1.25 MB
    unsigned short* WhTg = (unsigned short*)(ws + 311689216ull);    // 2 MB
    // hfp/hm overlap the Ab region (Ab dead once gemm_xp completes)
    unsigned*       hfp  = (unsigned*)(ws + 268435456ull);          // 256 KB
    float*          hm   = (float*)(ws + 268435456ull + 262144ull); // 128 KB

    hipLaunchKernelGGL(cvt_essays, dim3(81920), dim3(256), 0, stream, essays, Ab);
    hipLaunchKernelGGL(cvt_misc,   dim3(2560),  dim3(256), 0, stream, W_lstm, Bt);
    hipLaunchKernelGGL(cvt_wh,     dim3(4096),  dim3(256), 0, stream, W_lstm, WhTg);
    hipLaunchKernelGGL(gemm_xp,    dim3(8192),  dim3(256), 0, stream, Ab, Bt, b_lstm, xp);
    hipLaunchKernelGGL(lstm_rec,   dim3(16),    dim3(256), 0, stream, WhTg, xp, hfp, hm);
    hipLaunchKernelGGL(dense_out,  dim3(64),    dim3(64),  0, stream, hm, W_dense, b_dense, out);
}

// Round 2
// 5030.022 us; speedup vs baseline: 2.3544x; 2.3544x over previous
//
#include <hip/hip_runtime.h>
#include <hip/hip_bf16.h>
#include <stdint.h>

#define B_   64
#define T_   1024
#define D_   300
#define H_   512
#define G4H  2048
#define KP   320   // K padded to multiple of 32 for the x-proj GEMM

typedef __attribute__((ext_vector_type(8))) short short8;   // 8 x bf16 (4 VGPRs)
typedef __attribute__((ext_vector_type(4))) float f32x4;
typedef unsigned long long ull;

__device__ __forceinline__ unsigned short f2bf(float v) {
    __hip_bfloat16 h = __float2bfloat16(v);
    return *reinterpret_cast<unsigned short*>(&h);
}
__device__ __forceinline__ float bf2f(unsigned u) {      // low 16 bits = bf16
    return __uint_as_float(u << 16);
}
__device__ __forceinline__ float sigm(float x) { return 1.f / (1.f + __expf(-x)); }
__device__ __forceinline__ float tanhfast(float x) {
    float e = __expf(2.f * x);            // inf-safe: x>>0 -> 1, x<<0 -> -1
    return 1.f - 2.f / (e + 1.f);
}

// LDS-only barrier: does NOT drain vmcnt (unlike __syncthreads, which emits
// s_waitcnt vmcnt(0) before s_barrier and would serialize our fire-and-forget
// stores + in-flight polls/prefetches into the critical path).
__device__ __forceinline__ void bar_lds() {
    asm volatile("s_waitcnt lgkmcnt(0)" ::: "memory");
    __builtin_amdgcn_s_barrier();
    asm volatile("" ::: "memory");
}

#define ASYNC16(g, l)                                                        \
    __builtin_amdgcn_global_load_lds(                                        \
        (const __attribute__((address_space(1))) void*)(g),                  \
        (__attribute__((address_space(3))) void*)(l), 16, 0, 0)

// ---------------------------------------------------------------------------
// Kernel 1: essays fp32 [65536][300] -> bf16 [65536][320] (zero-padded K)
// ---------------------------------------------------------------------------
__global__ void cvt_essays(const float* __restrict__ es, unsigned short* __restrict__ Ab) {
    unsigned i = blockIdx.x * 256u + threadIdx.x;       // exactly 65536*320 threads
    unsigned row = i / KP;
    unsigned col = i - row * KP;
    float v = (col < D_) ? es[(size_t)row * D_ + col] : 0.f;
    Ab[i] = f2bf(v);
}

// ---------------------------------------------------------------------------
// Kernel 2: Wx transpose+pad -> bf16 WxT[2048][320]
// ---------------------------------------------------------------------------
__global__ void cvt_misc(const float* __restrict__ Wl, unsigned short* __restrict__ Bt) {
    unsigned i = blockIdx.x * 256u + threadIdx.x;       // exactly 2048*320 threads
    unsigned n = i / KP, k = i - n * KP;
    float v = (k < D_) ? Wl[(size_t)k * G4H + n] : 0.f;   // Wx rows 0..299
    Bt[i] = f2bf(v);
}

// ---------------------------------------------------------------------------
// Kernel 2b: Wh transpose -> bf16 WhTg[2048][512] (coalesced block staging)
// ---------------------------------------------------------------------------
__global__ void cvt_wh(const float* __restrict__ Wl, unsigned short* __restrict__ WhTg) {
    unsigned i = blockIdx.x * 256u + threadIdx.x;       // 2048*512 threads
    unsigned gc = i & 2047u, k = i >> 11;
    WhTg[(size_t)gc * 512 + k] = f2bf(Wl[(size_t)(300 + k) * G4H + gc]);
}

// ---------------------------------------------------------------------------
// Kernel 2c: poison both hfp step-buffers with tag-2 dwords (0xAAAAAAAA) so a
// consumer's first read (want tag 0) can never accept stale pre-LSTM bytes.
// Must run AFTER gemm_xp (hfp overlaps the Ab region).
// ---------------------------------------------------------------------------
__global__ void poison_hfp(unsigned* __restrict__ hfp) {
    hfp[blockIdx.x * 256u + threadIdx.x] = 0xAAAAAAAAu;   // 256 blocks -> 64K dwords
}

// ---------------------------------------------------------------------------
// Kernel 3: x_proj GEMM -> xpr in the recurrence layout:
//   per (t, g=batch-group, sl=j-slice of 32): 256 thread-slots x 8 bf16
//   idx = (((t*4+g)*16+sl)*256 + tid)*8 + u*4 + gate
// where the lstm thread tid = w*64 + q*16 + ln owns
//   b  = q*4 + (ln&3),  jl(u) = w*8 + u*4 + (ln>>2),  u in {0,1}
// so each lstm thread reads ONE 16B chunk per step.
// ---------------------------------------------------------------------------
__global__ __launch_bounds__(256) void gemm_xp(
    const unsigned short* __restrict__ Ab,   // [65536][320] bf16
    const unsigned short* __restrict__ Bt,   // [2048][320]  bf16 (WxT)
    const float* __restrict__ bias,          // [2048]
    unsigned short* __restrict__ xpr)        // [65536*2048] bf16, permuted
{
    __shared__ __align__(16) unsigned short Al[128 * 32];
    __shared__ __align__(16) unsigned short Bl[128 * 32];
    const int tid = threadIdx.x;
    const int w = tid >> 6, lane = tid & 63;
    const int ln = lane & 15, q = lane >> 4;
    const int bx = blockIdx.x;
    const int m0 = (bx >> 4) * 128;          // consecutive blocks share the A tile
    const int n0 = (bx & 15) * 128;
    const int wr = w >> 1, wc = w & 1;

    f32x4 acc[4][4];
#pragma unroll
    for (int i = 0; i < 4; i++)
#pragma unroll
        for (int j = 0; j < 4; j++) acc[i][j] = (f32x4){0.f, 0.f, 0.f, 0.f};

    for (int k0 = 0; k0 < KP; k0 += 32) {
#pragma unroll
        for (int it = 0; it < 2; ++it) {
            int s = it * 4 + w;              // wave-uniform segment id
            int c = s * 64 + lane;           // 16B chunk id, 0..511
            int r = c >> 2;                  // tile row 0..127
            int ko = (c & 3) * 8;            // k offset in elements
            ASYNC16(Ab + (size_t)(m0 + r) * KP + k0 + ko, &Al[s * 512]);
            ASYNC16(Bt + (size_t)(n0 + r) * KP + k0 + ko, &Bl[s * 512]);
        }
        __syncthreads();
        short8 af[4], bf[4];
#pragma unroll
        for (int mt = 0; mt < 4; ++mt)
            af[mt] = *(const short8*)&Al[(wr * 64 + mt * 16 + ln) * 32 + q * 8];
#pragma unroll
        for (int nt = 0; nt < 4; ++nt)
            bf[nt] = *(const short8*)&Bl[(wc * 64 + nt * 16 + ln) * 32 + q * 8];
#pragma unroll
        for (int mt = 0; mt < 4; ++mt)
#pragma unroll
            for (int nt = 0; nt < 4; ++nt)
                acc[mt][nt] = __builtin_amdgcn_mfma_f32_16x16x32_bf16(af[mt], bf[nt], acc[mt][nt], 0, 0, 0);
        __syncthreads();
    }
#pragma unroll
    for (int mt = 0; mt < 4; ++mt) {
#pragma unroll
        for (int nt = 0; nt < 4; ++nt) {
            int col = n0 + wc * 64 + nt * 16 + ln;
            int gate = col >> 9, j9 = col & 511;
            int sl = j9 >> 5, jl = j9 & 31;
            int wq  = jl >> 3;               // lstm wave
            int uu  = (jl >> 2) & 1;         // lstm col-tile
            int kk2 = jl & 3;                // lstm (ln>>2)
            float bb = bias[col];
#pragma unroll
            for (int r = 0; r < 4; ++r) {
                int row = m0 + wr * 64 + mt * 16 + q * 4 + r;   // C/D: col=lane&15, row=quad*4+reg
                int t = row & 1023, bglob = row >> 10;
                int g = bglob >> 4, b = bglob & 15;
                int tidl = wq * 64 + (b >> 2) * 16 + kk2 * 4 + (b & 3);
                size_t idx = ((((size_t)t * 4 + g) * 16 + sl) * 256 + tidl) * 8
                             + uu * 4 + gate;
                xpr[idx] = f2bf(acc[mt][nt][r] + bb);
            }
        }
    }
}

// ---------------------------------------------------------------------------
// Kernel 4: persistent LSTM recurrence. 64 blocks = 4 groups x 16 j-slices
// (32 j's each), 256 threads. One group per block (groups overlap in
// wall-clock as parallel blocks); the optimization target is the per-step
// chain latency:  store h -> visible -> poll -> decode -> bar -> MFMA ->
// shfl-transpose -> elementwise -> store.
//   - Wh slice in REGISTERS (bv[2][16] = 128 VGPR); LDS holds only hl (16.6KB).
//   - Gate-interleaved cols + 4-lane shfl transpose: no gbuf round-trip.
//   - bar_lds() (lgkmcnt-only raw s_barrier): stores are NEVER drained on the
//     critical path; polls and the xp prefetch stay in flight across barriers.
//     bar1 = RAW (decode-writes -> MFMA-reads); bar2 = WAR (MFMA-reads done
//     before any wave's next-step decode-writes).
//   - h stored EARLY in the step (right after MFMA+transpose), consumed late
//     next step: maximizes store->consume slack across the period.
//   - polls for h(t+1) pre-issued right after our stores; first check next
//     step, per-dword tag retry loop (protocol identical to the proven one:
//     fp32 h, 2-bit step tag mod 4 in mantissa LSBs, [2][64][512] buffers,
//     skew<=1, poison tag 2 never matches first-read want=0).
// ---------------------------------------------------------------------------
__global__ __launch_bounds__(256, 1) void lstm_rec(
    const unsigned short* __restrict__ WhTg, // [2048][512] bf16 (pre-transposed Wh)
    const unsigned short* __restrict__ xpr,  // permuted x_proj (see gemm_xp)
    unsigned* __restrict__ hfp,              // [2][64][512] fp32 h, tag in low bits
    float* __restrict__ hmean)               // [64][512] fp32
{
    __shared__ __align__(16) unsigned short hl[16 * 520];    // [b][j] pad 520

    const int tid = threadIdx.x;
    const int g   = blockIdx.x >> 4;         // batch group 0..3
    const int sl  = blockIdx.x & 15;         // j-slice 0..15 (32 j's)
    const int w = tid >> 6, lane = tid & 63, ln = lane & 15, q = lane >> 4;
    const int m = ln & 3;

    // ---- one-time: this wave's 32 Wh columns (gate-interleaved) -> registers
    short8 bv[2][16];
#pragma unroll
    for (int u = 0; u < 2; ++u) {
        int gc = (ln & 3) * 512 + 32 * sl + w * 8 + u * 4 + (ln >> 2);
        const unsigned short* wp = WhTg + (size_t)gc * 512 + q * 8;
#pragma unroll
        for (int kk = 0; kk < 16; ++kk)
            bv[u][kk] = *(const short8*)(wp + kk * 32);
    }
    // ---- h(0) = 0
    for (int i2 = tid; i2 < 4160; i2 += 256) ((unsigned*)hl)[i2] = 0u;
    __syncthreads();                          // one-time full barrier is fine

    float cst[2]  = {0.f, 0.f};
    float hsum[2] = {0.f, 0.f};
    short8 xc = *(const short8*)&xpr[(((size_t)g * 16 + sl) * 256 + tid) * 8];
    short8 xn;
    ull v[16];                                // in-flight poll registers

    for (int t = 0; t < T_; ++t) {
        // ---- xp(t+1) prefetch (one 16B load; consumed at end of this step)
        if (t + 1 < T_)
            xn = *(const short8*)&xpr[((((size_t)(t + 1) * 4 + g) * 16 + sl) * 256 + tid) * 8];

        // ---- consume h_g(t): check pre-issued polls, retry bad chunks
        if (t > 0) {
            const ull* src = (const ull*)(hfp + (size_t)(t & 1) * 32768 + g * 8192);
            const unsigned want = (unsigned)((t >> 1) & 3);
            while (true) {
                unsigned bad = 0u;
#pragma unroll
                for (int i = 0; i < 16; ++i) {
                    unsigned lo = (unsigned)v[i], hi = (unsigned)(v[i] >> 32);
                    bad |= ((((lo & 3u) ^ want) | ((hi & 3u) ^ want)) != 0u) ? (1u << i) : 0u;
                }
                if (!bad) break;
#pragma unroll
                for (int i = 0; i < 16; ++i)
                    if (bad & (1u << i))
                        v[i] = __hip_atomic_load(src + tid + (i << 8),
                                                 __ATOMIC_RELAXED, __HIP_MEMORY_SCOPE_AGENT);
            }
            // decode fp32(tagged) -> bf16 pair -> hl; thread owns col-pair tid
#pragma unroll
            for (int i = 0; i < 16; ++i) {
                unsigned uu = (unsigned)f2bf(__uint_as_float((unsigned)v[i]))
                            | ((unsigned)f2bf(__uint_as_float((unsigned)(v[i] >> 32))) << 16);
                *(unsigned*)((char*)hl + i * 1040 + tid * 4) = uu;
            }
        }
        bar_lds();                            // bar1: RAW on hl (no vmcnt drain)

        // ---- gates = h_g(t) @ Wh-slice : 2 col-tiles x 2 K-half chains
        f32x4 a0 = (f32x4){0.f,0.f,0.f,0.f}, a1 = (f32x4){0.f,0.f,0.f,0.f};
        f32x4 b0 = (f32x4){0.f,0.f,0.f,0.f}, b1 = (f32x4){0.f,0.f,0.f,0.f};
#pragma unroll
        for (int kk = 0; kk < 8; ++kk) {
            short8 av = *(const short8*)&hl[ln * 520 + kk * 32 + q * 8];
            a0 = __builtin_amdgcn_mfma_f32_16x16x32_bf16(av, bv[0][kk], a0, 0, 0, 0);
            a1 = __builtin_amdgcn_mfma_f32_16x16x32_bf16(av, bv[1][kk], a1, 0, 0, 0);
        }
#pragma unroll
        for (int kk = 8; kk < 16; ++kk) {
            short8 av = *(const short8*)&hl[ln * 520 + kk * 32 + q * 8];
            b0 = __builtin_amdgcn_mfma_f32_16x16x32_bf16(av, bv[0][kk], b0, 0, 0, 0);
            b1 = __builtin_amdgcn_mfma_f32_16x16x32_bf16(av, bv[1][kk], b1, 0, 0, 0);
        }
        bar_lds();                            // bar2: WAR on hl (reads retired)

        // ---- per col-tile: 4x4 transpose in 4-lane groups, elementwise, store
#pragma unroll
        for (int u = 0; u < 2; ++u) {
            f32x4 ca = u ? a1 : a0, cb = u ? b1 : b0;
            float x0 = ca[0] + cb[0], x1 = ca[1] + cb[1];
            float x2 = ca[2] + cb[2], x3 = ca[3] + cb[3];
            float s0 = (m & 1) ? x0 : x1, s1 = (m & 1) ? x2 : x3;
            s0 = __shfl_xor(s0, 1); s1 = __shfl_xor(s1, 1);
            if (m & 1) { x0 = s0; x2 = s1; } else { x1 = s0; x3 = s1; }
            float u0 = (m & 2) ? x0 : x2, u1 = (m & 2) ? x1 : x3;
            u0 = __shfl_xor(u0, 2); u1 = __shfl_xor(u1, 2);
            if (m & 2) { x0 = u0; x1 = u1; } else { x2 = u0; x3 = u1; }
            // x0..x3 = i,j,f,o (Wh part) for (b=q*4+m, jl=w*8+u*4+(ln>>2))
            float ai  = x0 + bf2f((unsigned)(unsigned short)xc[u * 4 + 0]);
            float aj  = x1 + bf2f((unsigned)(unsigned short)xc[u * 4 + 1]);
            float af_ = x2 + bf2f((unsigned)(unsigned short)xc[u * 4 + 2]);
            float ao  = x3 + bf2f((unsigned)(unsigned short)xc[u * 4 + 3]);
            float si = sigm(ai), tj = tanhfast(aj);
            float sf = sigm(af_ + 1.0f), so = sigm(ao);
            cst[u] = cst[u] * sf + si * tj;
            float h = tanhfast(cst[u]) * so;
            hsum[u] += h;
            unsigned hb = (__float_as_uint(h) & ~3u) | (unsigned)(((t + 1) >> 1) & 3);
            int b = q * 4 + m, jl = w * 8 + u * 4 + (ln >> 2);
            __hip_atomic_store(hfp + (size_t)((t + 1) & 1) * 32768 + (g * 16 + b) * 512 + 32 * sl + jl,
                               hb, __ATOMIC_RELAXED, __HIP_MEMORY_SCOPE_AGENT);
        }
        xc = xn;

        // ---- pre-issue polls for h_g(t+1): RTT overlaps the loop tail + the
        // other blocks' store window; consumed (with retry) at t+1.
        if (t + 1 < T_) {
            const ull* src2 = (const ull*)(hfp + (size_t)((t + 1) & 1) * 32768 + g * 8192);
#pragma unroll
            for (int i = 0; i < 16; ++i)
                v[i] = __hip_atomic_load(src2 + tid + (i << 8),
                                         __ATOMIC_RELAXED, __HIP_MEMORY_SCOPE_AGENT);
        }
    }
#pragma unroll
    for (int u = 0; u < 2; ++u) {
        int b = q * 4 + m, jl = w * 8 + u * 4 + (ln >> 2);
        hmean[(size_t)(g * 16 + b) * 512 + 32 * sl + jl] = hsum[u] * (1.f / 1024.f);
    }
}

// ---------------------------------------------------------------------------
// Kernel 5: preds = sigmoid(hmean @ W_dense + b_dense), one wave per batch row
// ---------------------------------------------------------------------------
__global__ void dense_out(const float* __restrict__ hmean, const float* __restrict__ Wd,
                          const float* __restrict__ bd, float* __restrict__ out) {
    int bb = blockIdx.x;
    int lane = threadIdx.x;
    float p = 0.f;
    for (int e = lane; e < H_; e += 64) p += hmean[(size_t)bb * H_ + e] * Wd[e];
#pragma unroll
    for (int off = 32; off; off >>= 1) p += __shfl_down(p, off);
    if (lane == 0) out[bb] = 1.f / (1.f + __expf(-(p + bd[0])));
}

// ---------------------------------------------------------------------------
extern "C" void kernel_launch(void* const* d_in, const int* in_sizes, int n_in,
                              void* d_out, int out_size, void* d_ws, size_t ws_size,
                              hipStream_t stream) {
    const float* essays  = (const float*)d_in[0];
    const float* W_lstm  = (const float*)d_in[1];
    const float* b_lstm  = (const float*)d_in[2];
    const float* W_dense = (const float*)d_in[3];
    const float* b_dense = (const float*)d_in[4];
    float* out = (float*)d_out;

    char* ws = (char*)d_ws;
    unsigned short* xp   = (unsigned short*)(ws);                   // 256 MB (permuted)
    unsigned short* Ab   = (unsigned short*)(ws + 268435456ull);    // 40 MB (dead after gemm_xp)
    unsigned short* Bt   = (unsigned short*)(ws + 310378496ull);    // 1.25 MB
    unsigned short* WhTg = (unsigned short*)(ws + 311689216ull);    // 2 MB
    // hfp/hm overlap the Ab region (Ab dead once gemm_xp completes)
    unsigned*       hfp  = (unsigned*)(ws + 268435456ull);          // 256 KB
    float*          hm   = (float*)(ws + 268435456ull + 262144ull); // 128 KB

    hipLaunchKernelGGL(cvt_essays, dim3(81920), dim3(256), 0, stream, essays, Ab);
    hipLaunchKernelGGL(cvt_misc,   dim3(2560),  dim3(256), 0, stream, W_lstm, Bt);
    hipLaunchKernelGGL(cvt_wh,     dim3(4096),  dim3(256), 0, stream, W_lstm, WhTg);
    hipLaunchKernelGGL(gemm_xp,    dim3(8192),  dim3(256), 0, stream, Ab, Bt, b_lstm, xp);
    hipLaunchKernelGGL(poison_hfp, dim3(256),   dim3(256), 0, stream, hfp);
    hipLaunchKernelGGL(lstm_rec,   dim3(64),    dim3(256), 0, stream, WhTg, xp, hfp, hm);
    hipLaunchKernelGGL(dense_out,  dim3(64),    dim3(64),  0, stream, hm, W_dense, b_dense, out);
}